// Round 7
// baseline (115.057 us; speedup 1.0000x reference)
//
#include <hip/hip_runtime.h>
#include <math.h>

// Problem constants (fixed by the reference file)
constexpr int B  = 1024;
constexpr int NL = 64;
constexpr int W  = 2048;
constexpr int INNER = NL - 2;   // layers 1..62
constexpr float EPS_N = 1e-8f;
constexpr float EPS_Y = 1e-9f;

// TRANS-FREE TMM. Per-layer matrix only matters up to scalar scale (scale
// commutes through the product and cancels in Y = H/E, hence in R). With
// h = tan(pi*r) approximated by the [5/4] Pade N(r)/D(r) (pole of D at
// x=1.57073 ~ pi/2, phase err ~3e-6 rad):
//     cos(2*pi*r) ~ D^2 - N^2,   sin(2*pi*r) ~ 2*N*D   (common scale D^2+N^2)
// -- all polynomial, no v_sin/v_cos (16 issue-cy each at wave64; they were
// ~52% of the round-5 issue budget).
// N,D coefficients pre-divided by 1010 so the per-layer scale D^2+N^2 lies in
// [0.875, 1.158]; worst-case 62-layer drift e^~9 stays comfortably in fp32.
//
// Per wavelength-layer: 22 VALU ops, 0 trans.
//   phi=nd/lam; r=phi-rint(phi); y=r^2
//   N = r*(cn0 + cn1*y + cn2*y^2); D = cd0 + cd1*y + cd2*y^2
//   C = D^2 - N^2; ND = N*D; ns = (2n)*ND; is = (2/(n+eps))*ND
//   a' = b*ns + a*C; b' = -a*is + b*C; c' = -d*ns + c*C; d' = c*is + d*C
__global__ __launch_bounds__(256)
void tmm_kernel(const float* __restrict__ n_layers,
                const float* __restrict__ d_layers,
                const float* __restrict__ wavelengths,
                float* __restrict__ out)
{
    // [5/4] Pade of tan(pi*r) in revolutions, y = r^2, all coeffs / 1010:
    //   N(r) = r*(945*pi - 105*pi^3 y + pi^5 y^2) / 1010
    //   D(r) = (945 - 420*pi^2 y + 15*pi^4 y^2) / 1010
    constexpr float cn0 =  2.9394112f;   // 945*pi    / 1010
    constexpr float cn1 = -3.2234247f;   // -105*pi^3 / 1010
    constexpr float cn2 =  0.3029898f;   // pi^5      / 1010
    constexpr float cd0 =  0.9356436f;   // 945       / 1010
    constexpr float cd1 = -4.1041920f;   // -420*pi^2 / 1010
    constexpr float cd2 =  1.4466696f;   // 15*pi^4   / 1010

    __shared__ float4 s_layer[INNER];   // (n*d, 2n, 2/(n+eps), pad)
    __shared__ float s_edge[2];         // n_in, n_sub

    const int b   = blockIdx.y;
    const int tid = threadIdx.x;
    const int w0  = blockIdx.x * 256 + tid;        // first wavelength
    const int w1  = w0 + (W / 2);                  // second wavelength

    if (tid < INNER) {
        const float n = n_layers[b * NL + 1 + tid];
        const float d = d_layers[b * NL + 1 + tid];
        s_layer[tid] = make_float4(n * d, 2.0f * n, 2.0f / (n + EPS_N), 0.0f);
    }
    if (tid == INNER) {
        s_edge[0] = n_layers[b * NL];              // n_in
        s_edge[1] = n_layers[b * NL + NL - 1];     // n_sub
    }
    __syncthreads();

    const float il0 = 1.0f / wavelengths[w0];      // k0 in revolutions
    const float il1 = 1.0f / wavelengths[w1];

    float a0 = 1.0f, b0 = 0.0f, c0 = 0.0f, d0 = 1.0f;
    float a1 = 1.0f, b1 = 0.0f, c1 = 0.0f, d1 = 1.0f;

    #pragma unroll 2
    for (int i = 0; i < INNER; ++i) {
        const float4 L = s_layer[i];

        {   // chain 0
            const float phi = L.x * il0;
            const float r   = phi - __builtin_rintf(phi);
            const float y   = r * r;
            const float Np  = fmaf(y, fmaf(y, cn2, cn1), cn0) * r;
            const float Dp  = fmaf(y, fmaf(y, cd2, cd1), cd0);
            const float C   = fmaf(Np, -Np, Dp * Dp);
            const float ND  = Np * Dp;
            const float ns  = L.y * ND;            // 2n * ND
            const float is  = L.z * ND;            // 2/(n+eps) * ND
            const float na = fmaf(b0,  ns, a0 * C);
            const float nb = fmaf(a0, -is, b0 * C);
            const float nc = fmaf(d0, -ns, c0 * C);
            const float nd = fmaf(c0,  is, d0 * C);
            a0 = na; b0 = nb; c0 = nc; d0 = nd;
        }
        {   // chain 1
            const float phi = L.x * il1;
            const float r   = phi - __builtin_rintf(phi);
            const float y   = r * r;
            const float Np  = fmaf(y, fmaf(y, cn2, cn1), cn0) * r;
            const float Dp  = fmaf(y, fmaf(y, cd2, cd1), cd0);
            const float C   = fmaf(Np, -Np, Dp * Dp);
            const float ND  = Np * Dp;
            const float ns  = L.y * ND;
            const float is  = L.z * ND;
            const float na = fmaf(b1,  ns, a1 * C);
            const float nb = fmaf(a1, -is, b1 * C);
            const float nc = fmaf(d1, -ns, c1 * C);
            const float nd = fmaf(c1,  is, d1 * C);
            a1 = na; b1 = nb; c1 = nc; d1 = nd;
        }
    }

    const float n_in  = s_edge[0];
    const float n_sub = s_edge[1];

    {
        const float Er = a0 + EPS_Y;
        const float Ei = b0 * n_sub;
        const float Hr = d0 * n_sub;
        const float Hi = c0;
        const float Nr = fmaf(n_in, Er, -Hr);
        const float Ni = fmaf(n_in, Ei, -Hi);
        const float Dr = fmaf(n_in, Er,  Hr);
        const float Di = fmaf(n_in, Ei,  Hi);
        out[b * W + w0] = (Nr * Nr + Ni * Ni) / (Dr * Dr + Di * Di);
    }
    {
        const float Er = a1 + EPS_Y;
        const float Ei = b1 * n_sub;
        const float Hr = d1 * n_sub;
        const float Hi = c1;
        const float Nr = fmaf(n_in, Er, -Hr);
        const float Ni = fmaf(n_in, Ei, -Hi);
        const float Dr = fmaf(n_in, Er,  Hr);
        const float Di = fmaf(n_in, Ei,  Hi);
        out[b * W + w1] = (Nr * Nr + Ni * Ni) / (Dr * Dr + Di * Di);
    }
}

extern "C" void kernel_launch(void* const* d_in, const int* in_sizes, int n_in,
                              void* d_out, int out_size, void* d_ws, size_t ws_size,
                              hipStream_t stream)
{
    const float* n_layers    = (const float*)d_in[0];
    const float* d_layers    = (const float*)d_in[1];
    const float* wavelengths = (const float*)d_in[2];
    float* out = (float*)d_out;

    dim3 grid((W / 2) / 256, B);   // 4 x 1024 blocks, 2 wavelengths/thread
    dim3 block(256);
    tmm_kernel<<<grid, block, 0, stream>>>(n_layers, d_layers, wavelengths, out);
}

// Round 8
// 108.520 us; speedup vs baseline: 1.0602x; 1.0602x over previous
//
#include <hip/hip_runtime.h>
#include <math.h>

// Problem constants (fixed by the reference file)
constexpr int B  = 1024;
constexpr int NL = 64;
constexpr int W  = 2048;
constexpr int INNER = NL - 2;   // layers 1..62
constexpr float EPS_N = 1e-8f;
constexpr float EPS_Y = 1e-9f;

// Issue-floor structure (round-5 math, measured 38 cy/wavelength-layer):
// per wavelength-layer exactly 11 VALU (2cy) + sin + cos (8cy trans each).
// phi in REVOLUTIONS so v_sin/v_cos need zero range reduction.
//
// This round: 4 wavelengths/thread (4 independent chains hide trans latency)
// and a perfectly balanced grid: 2048 blocks = 8 blocks/CU x 4 waves
// = 32 waves/CU resident in ONE round (no tail imbalance).
__global__ __launch_bounds__(256, 8)
void tmm_kernel(const float* __restrict__ n_layers,
                const float* __restrict__ d_layers,
                const float* __restrict__ wavelengths,
                float* __restrict__ out)
{
    __shared__ float4 s_layer[INNER];   // (n*d, n, 1/(n+eps), pad)
    __shared__ float s_edge[2];         // n_in, n_sub

    const int b   = blockIdx.y;
    const int tid = threadIdx.x;
    const int w0  = blockIdx.x * 256 + tid;        // w0 in [0, 512)

    if (tid < INNER) {
        const float n = n_layers[b * NL + 1 + tid];
        const float d = d_layers[b * NL + 1 + tid];
        s_layer[tid] = make_float4(n * d, n, 1.0f / (n + EPS_N), 0.0f);
    }
    if (tid == INNER) {
        s_edge[0] = n_layers[b * NL];              // n_in
        s_edge[1] = n_layers[b * NL + NL - 1];     // n_sub
    }
    __syncthreads();

    const float il0 = 1.0f / wavelengths[w0];           // k0 in revolutions
    const float il1 = 1.0f / wavelengths[w0 + 512];
    const float il2 = 1.0f / wavelengths[w0 + 1024];
    const float il3 = 1.0f / wavelengths[w0 + 1536];

    // 4 independent chains, state M = [[a, i*b],[i*c, d]], identity start.
    float a0 = 1.f, b0 = 0.f, c0 = 0.f, d0 = 1.f;
    float a1 = 1.f, b1 = 0.f, c1 = 0.f, d1 = 1.f;
    float a2 = 1.f, b2 = 0.f, c2 = 0.f, d2 = 1.f;
    float a3 = 1.f, b3 = 0.f, c3 = 0.f, d3 = 1.f;

    #pragma unroll
    for (int i = 0; i < INNER; ++i) {
        const float4 L = s_layer[i];

        // Issue all 8 trans ops up front (independent) so the VALU work of
        // one chain overlaps the trans latency of the others.
        const float p0 = L.x * il0;
        const float p1 = L.x * il1;
        const float p2 = L.x * il2;
        const float p3 = L.x * il3;
        const float s0 = __builtin_amdgcn_sinf(p0);
        const float q0 = __builtin_amdgcn_cosf(p0);
        const float s1 = __builtin_amdgcn_sinf(p1);
        const float q1 = __builtin_amdgcn_cosf(p1);
        const float s2 = __builtin_amdgcn_sinf(p2);
        const float q2 = __builtin_amdgcn_cosf(p2);
        const float s3 = __builtin_amdgcn_sinf(p3);
        const float q3 = __builtin_amdgcn_cosf(p3);

        {
            const float ns = L.y * s0, is = L.z * s0;
            const float na = fmaf(b0,  ns, a0 * q0);
            const float nb = fmaf(a0, -is, b0 * q0);
            const float nc = fmaf(d0, -ns, c0 * q0);
            const float nd = fmaf(c0,  is, d0 * q0);
            a0 = na; b0 = nb; c0 = nc; d0 = nd;
        }
        {
            const float ns = L.y * s1, is = L.z * s1;
            const float na = fmaf(b1,  ns, a1 * q1);
            const float nb = fmaf(a1, -is, b1 * q1);
            const float nc = fmaf(d1, -ns, c1 * q1);
            const float nd = fmaf(c1,  is, d1 * q1);
            a1 = na; b1 = nb; c1 = nc; d1 = nd;
        }
        {
            const float ns = L.y * s2, is = L.z * s2;
            const float na = fmaf(b2,  ns, a2 * q2);
            const float nb = fmaf(a2, -is, b2 * q2);
            const float nc = fmaf(d2, -ns, c2 * q2);
            const float nd = fmaf(c2,  is, d2 * q2);
            a2 = na; b2 = nb; c2 = nc; d2 = nd;
        }
        {
            const float ns = L.y * s3, is = L.z * s3;
            const float na = fmaf(b3,  ns, a3 * q3);
            const float nb = fmaf(a3, -is, b3 * q3);
            const float nc = fmaf(d3, -ns, c3 * q3);
            const float nd = fmaf(c3,  is, d3 * q3);
            a3 = na; b3 = nb; c3 = nc; d3 = nd;
        }
    }

    const float n_in  = s_edge[0];
    const float n_sub = s_edge[1];

    // E = a + eps_Y + i*(b*n_sub);  H = d*n_sub + i*c;  R = |nE-H|^2/|nE+H|^2
    {
        const float Er = a0 + EPS_Y, Ei = b0 * n_sub, Hr = d0 * n_sub, Hi = c0;
        const float Nr = fmaf(n_in, Er, -Hr), Ni = fmaf(n_in, Ei, -Hi);
        const float Dr = fmaf(n_in, Er,  Hr), Di = fmaf(n_in, Ei,  Hi);
        out[b * W + w0] = (Nr * Nr + Ni * Ni) / (Dr * Dr + Di * Di);
    }
    {
        const float Er = a1 + EPS_Y, Ei = b1 * n_sub, Hr = d1 * n_sub, Hi = c1;
        const float Nr = fmaf(n_in, Er, -Hr), Ni = fmaf(n_in, Ei, -Hi);
        const float Dr = fmaf(n_in, Er,  Hr), Di = fmaf(n_in, Ei,  Hi);
        out[b * W + w0 + 512] = (Nr * Nr + Ni * Ni) / (Dr * Dr + Di * Di);
    }
    {
        const float Er = a2 + EPS_Y, Ei = b2 * n_sub, Hr = d2 * n_sub, Hi = c2;
        const float Nr = fmaf(n_in, Er, -Hr), Ni = fmaf(n_in, Ei, -Hi);
        const float Dr = fmaf(n_in, Er,  Hr), Di = fmaf(n_in, Ei,  Hi);
        out[b * W + w0 + 1024] = (Nr * Nr + Ni * Ni) / (Dr * Dr + Di * Di);
    }
    {
        const float Er = a3 + EPS_Y, Ei = b3 * n_sub, Hr = d3 * n_sub, Hi = c3;
        const float Nr = fmaf(n_in, Er, -Hr), Ni = fmaf(n_in, Ei, -Hi);
        const float Dr = fmaf(n_in, Er,  Hr), Di = fmaf(n_in, Ei,  Hi);
        out[b * W + w0 + 1536] = (Nr * Nr + Ni * Ni) / (Dr * Dr + Di * Di);
    }
}

extern "C" void kernel_launch(void* const* d_in, const int* in_sizes, int n_in,
                              void* d_out, int out_size, void* d_ws, size_t ws_size,
                              hipStream_t stream)
{
    const float* n_layers    = (const float*)d_in[0];
    const float* d_layers    = (const float*)d_in[1];
    const float* wavelengths = (const float*)d_in[2];
    float* out = (float*)d_out;

    dim3 grid((W / 4) / 256, B);   // 2 x 1024 = 2048 blocks: exactly 8/CU
    dim3 block(256);
    tmm_kernel<<<grid, block, 0, stream>>>(n_layers, d_layers, wavelengths, out);
}